// Round 13
// baseline (148.648 us; speedup 1.0000x reference)
//
#include <hip/hip_runtime.h>
#include <math.h>

constexpr int K = 512;
constexpr int D = 64;
constexpr int HW = 64 * 64;                      // 4096
constexpr int NPIX = 131072;
constexpr long long NELEM = (long long)NPIX * D; // 8388608
constexpr float BETA = 0.25f;
constexpr int PPB = 128;                         // pixels per block
constexpr int NBLK = NPIX / PPB;                 // 1024 blocks

typedef __attribute__((ext_vector_type(8))) short short8;
typedef __attribute__((ext_vector_type(4))) float f32x4;

union frag_u { uint4 u; short8 s; };

__device__ inline unsigned short bf16rne(float x) {
    unsigned u = __float_as_uint(x);
    unsigned r = (u + 0x7FFFu + ((u >> 16) & 1u)) >> 16;
    return (unsigned short)r;
}

// truncated-bf16 pack: f0 -> low ushort, f1 -> high ushort (one v_perm_b32)
__device__ inline unsigned pk(float f0, float f1) {
    return __builtin_amdgcn_perm(__float_as_uint(f1), __float_as_uint(f0), 0x07060302u);
}

// Wave-specialized fused kernel: waves w and w+4 share 32 pixels, each scans
// half the codebook (halves the per-wave serial main loop); LDS min-merge.
__global__ __launch_bounds__(512, 4) void vq_one(
    const float* __restrict__ z, const float* __restrict__ E,
    float* __restrict__ out, int out_size, float* __restrict__ sse_arr,
    unsigned int* __restrict__ counts, unsigned int* __restrict__ ticket) {

    __shared__ __align__(16) unsigned short sb[32768];   // 64 KB B-frags
    __shared__ unsigned int eepk[K];                     // ee hi|lo packed bf16
    __shared__ float mb[8][32];                          // per-wave row bests
    __shared__ int bks[PPB];
    __shared__ unsigned int hcnt[K];
    __shared__ float red[8], red2[8];
    __shared__ int sflag;

    const int tid = threadIdx.x;
    const int wave = tid >> 6;      // 0..7
    const int wp = wave & 3;        // pixel-group
    const int chalf = wave >> 2;    // codebook half
    const int lane = tid & 63;
    const int quad = lane >> 4;     // k-group
    const int lx = lane & 15;       // m for A, n for B, col for C/D

    const int p0 = blockIdx.x * PPB;
    const int b = p0 >> 12;
    const int s0 = p0 & (HW - 1);

    hcnt[tid] = 0u;

    // ---- A loads: 32 px per wave-pair (wp), full K ----
    const float* zb = z + (size_t)b * (D * HW) + s0 + wp * 32;
    float z0[16], z1[16];   // row-tile 0 / 1
#pragma unroll
    for (int c = 0; c < 2; ++c)
#pragma unroll
        for (int j = 0; j < 8; ++j) {
            size_t doff = (size_t)(c * 32 + quad * 8 + j) * HW;
            z0[c * 8 + j] = zb[doff + lx];
            z1[c * 8 + j] = zb[doff + 16 + lx];
        }

    // ---- B build: thread = codebook row n (full B, 8 pipelined groups) ----
    {
        const int n = tid;
        const float4* er = (const float4*)(E + n * D);
        const int tile = n >> 4, col = n & 15;
        float acc = 0.f;
        float4 c0 = er[0], c1 = er[1];
#pragma unroll
        for (int g = 0; g < 8; ++g) {
            float4 n0, n1;
            if (g < 7) { n0 = er[2 * g + 2]; n1 = er[2 * g + 3]; }
            acc = fmaf(c0.x, c0.x, acc); acc = fmaf(c0.y, c0.y, acc);
            acc = fmaf(c0.z, c0.z, acc); acc = fmaf(c0.w, c0.w, acc);
            acc = fmaf(c1.x, c1.x, acc); acc = fmaf(c1.y, c1.y, acc);
            acc = fmaf(c1.z, c1.z, acc); acc = fmaf(c1.w, c1.w, acc);
            uint4 w;
            w.x = pk(-2.f * c0.x, -2.f * c0.y);
            w.y = pk(-2.f * c0.z, -2.f * c0.w);
            w.z = pk(-2.f * c1.x, -2.f * c1.y);
            w.w = pk(-2.f * c1.z, -2.f * c1.w);
            *(uint4*)&sb[(tile * 2 + (g >> 2)) * 512 + ((g & 3) * 16 + col) * 8] = w;
            c0 = n0; c1 = n1;
        }
        unsigned short eh = bf16rne(acc);
        unsigned short el = bf16rne(acc - __uint_as_float((unsigned)eh << 16));
        eepk[n] = (unsigned)eh | ((unsigned)el << 16);
    }

    // ---- A pack + ||z||^2 (only codebook-half-0 waves count zsq) ----
    frag_u a[2][2];
    float zsq = 0.f;
#pragma unroll
    for (int c = 0; c < 2; ++c) {
#pragma unroll
        for (int j = 0; j < 8; ++j) {
            zsq = fmaf(z0[c * 8 + j], z0[c * 8 + j], zsq);
            zsq = fmaf(z1[c * 8 + j], z1[c * 8 + j], zsq);
        }
        a[0][c].u.x = pk(z0[c * 8 + 0], z0[c * 8 + 1]);
        a[0][c].u.y = pk(z0[c * 8 + 2], z0[c * 8 + 3]);
        a[0][c].u.z = pk(z0[c * 8 + 4], z0[c * 8 + 5]);
        a[0][c].u.w = pk(z0[c * 8 + 6], z0[c * 8 + 7]);
        a[1][c].u.x = pk(z1[c * 8 + 0], z1[c * 8 + 1]);
        a[1][c].u.y = pk(z1[c * 8 + 2], z1[c * 8 + 3]);
        a[1][c].u.z = pk(z1[c * 8 + 4], z1[c * 8 + 5]);
        a[1][c].u.w = pk(z1[c * 8 + 6], z1[c * 8 + 7]);
    }
    if (chalf) zsq = 0.f;

    frag_u aee;
    aee.u.x = (quad == 0) ? 0x3F803F80u : 0u;
    aee.u.y = 0u; aee.u.z = 0u; aee.u.w = 0u;

    float best0[4], best1[4];
#pragma unroll
    for (int r = 0; r < 4; ++r) {
        best0[r] = __uint_as_float(0x7F800000u);
        best1[r] = __uint_as_float(0x7F800000u);
    }

    __syncthreads();   // B + eepk resident

    // ---- Main loop: 8 x 2 col-tiles (this wave's codebook half) ----
#pragma unroll 1
    for (int t2 = 0; t2 < 8; ++t2) {
        const int ta = chalf * 16 + 2 * t2, tb = ta + 1;
        frag_u ba0, ba1, bb0, bb1;
        ba0.u = *(const uint4*)&sb[(ta * 2 + 0) * 512 + lane * 8];
        ba1.u = *(const uint4*)&sb[(ta * 2 + 1) * 512 + lane * 8];
        bb0.u = *(const uint4*)&sb[(tb * 2 + 0) * 512 + lane * 8];
        bb1.u = *(const uint4*)&sb[(tb * 2 + 1) * 512 + lane * 8];
        frag_u beea, beeb;
        beea.u.x = (quad == 0) ? eepk[ta * 16 + lx] : 0u;
        beea.u.y = 0u; beea.u.z = 0u; beea.u.w = 0u;
        beeb.u.x = (quad == 0) ? eepk[tb * 16 + lx] : 0u;
        beeb.u.y = 0u; beeb.u.z = 0u; beeb.u.w = 0u;

        f32x4 aa0 = {0,0,0,0}, aa1 = {0,0,0,0}, ab0 = {0,0,0,0}, ab1 = {0,0,0,0};
        aa0 = __builtin_amdgcn_mfma_f32_16x16x32_bf16(a[0][0].s, ba0.s, aa0, 0, 0, 0);
        aa1 = __builtin_amdgcn_mfma_f32_16x16x32_bf16(a[1][0].s, ba0.s, aa1, 0, 0, 0);
        ab0 = __builtin_amdgcn_mfma_f32_16x16x32_bf16(a[0][0].s, bb0.s, ab0, 0, 0, 0);
        ab1 = __builtin_amdgcn_mfma_f32_16x16x32_bf16(a[1][0].s, bb0.s, ab1, 0, 0, 0);
        aa0 = __builtin_amdgcn_mfma_f32_16x16x32_bf16(a[0][1].s, ba1.s, aa0, 0, 0, 0);
        aa1 = __builtin_amdgcn_mfma_f32_16x16x32_bf16(a[1][1].s, ba1.s, aa1, 0, 0, 0);
        ab0 = __builtin_amdgcn_mfma_f32_16x16x32_bf16(a[0][1].s, bb1.s, ab0, 0, 0, 0);
        ab1 = __builtin_amdgcn_mfma_f32_16x16x32_bf16(a[1][1].s, bb1.s, ab1, 0, 0, 0);
        aa0 = __builtin_amdgcn_mfma_f32_16x16x32_bf16(aee.s, beea.s, aa0, 0, 0, 0);
        aa1 = __builtin_amdgcn_mfma_f32_16x16x32_bf16(aee.s, beea.s, aa1, 0, 0, 0);
        ab0 = __builtin_amdgcn_mfma_f32_16x16x32_bf16(aee.s, beeb.s, ab0, 0, 0, 0);
        ab1 = __builtin_amdgcn_mfma_f32_16x16x32_bf16(aee.s, beeb.s, ab1, 0, 0, 0);

        unsigned cba = (unsigned)(ta * 16 + lx), cbb = (unsigned)(tb * 16 + lx);
#pragma unroll
        for (int r = 0; r < 4; ++r) {
            float ka0 = __uint_as_float((__float_as_uint(aa0[r]) & 0xFFFFFE00u) | cba);
            float kb0 = __uint_as_float((__float_as_uint(ab0[r]) & 0xFFFFFE00u) | cbb);
            best0[r] = fminf(fminf(best0[r], ka0), kb0);
            float ka1 = __uint_as_float((__float_as_uint(aa1[r]) & 0xFFFFFE00u) | cba);
            float kb1 = __uint_as_float((__float_as_uint(ab1[r]) & 0xFFFFFE00u) | cbb);
            best1[r] = fminf(fminf(best1[r], ka1), kb1);
        }
    }

    // ---- Per-wave butterfly over cols; write row bests to mb[wave][] ----
#pragma unroll
    for (int rt = 0; rt < 2; ++rt) {
#pragma unroll
        for (int r = 0; r < 4; ++r) {
            float v = rt == 0 ? best0[r] : best1[r];
#pragma unroll
            for (int m = 1; m < 16; m <<= 1) v = fminf(v, __shfl_xor(v, m, 64));
            if (lx == 4 * quad + r) mb[wave][rt * 16 + 4 * quad + r] = v;
        }
    }
    __syncthreads();

    // ---- Merge halves (tid<128: one pixel each) + hist + SSE ----
    float lsse = zsq;
    if (tid < PPB) {
        int wp2 = tid >> 5, row = tid & 31;
        float v = fminf(mb[wp2][row], mb[wp2 + 4][row]);
        unsigned u = __float_as_uint(v);
        int c = (int)(u & 0x1FFu);
        bks[tid] = c;
        atomicAdd(&hcnt[c], 1u);
        lsse += __uint_as_float(u & 0xFFFFFE00u);
    }
#pragma unroll
    for (int off = 32; off > 0; off >>= 1) lsse += __shfl_down(lsse, off, 64);
    if (lane == 0) red[wave] = lsse;

    __syncthreads();
    if (tid == 0) {
        float s = 0.f;
#pragma unroll
        for (int i = 0; i < 8; ++i) s += red[i];
        sse_arr[blockIdx.x] = s;
    }

    // ---- Epilogue: thread -> (pixel = tid&127, d-quarter = tid>>7) ----
    {
        int q = tid & (PPB - 1);
        int dq = tid >> 7;               // 0..3 -> d 16*dq .. 16*dq+15
        int bk = bks[q];
        const float4* Er = (const float4*)(E + bk * D + dq * 16);
        float* ob = out + 1 + (size_t)b * (D * HW) + (size_t)dq * 16 * HW + s0 + q;
#pragma unroll
        for (int v4i = 0; v4i < 4; ++v4i) {
            float4 e4 = Er[v4i];
            ob[(size_t)(4 * v4i + 0) * HW] = e4.x;
            ob[(size_t)(4 * v4i + 1) * HW] = e4.y;
            ob[(size_t)(4 * v4i + 2) * HW] = e4.z;
            ob[(size_t)(4 * v4i + 3) * HW] = e4.w;
        }
    }

    // ---- flush histogram ----
    unsigned hc = hcnt[tid];
    if (hc) atomicAdd(&counts[tid], hc);

    // ---- fused finalize: last block computes loss + perplexity ----
    __syncthreads();
    if (tid == 0) {
        __threadfence();
        unsigned t = atomicAdd(ticket, 1u);
        sflag = (t == (unsigned)(NBLK - 1)) ? 1 : 0;
    }
    __syncthreads();
    if (sflag) {
        float cf = (float)atomicAdd(&counts[tid], 0u);
        float pa = cf / (float)NPIX + 1e-10f;
        float t = pa * logf(pa);
        float s = atomicAdd(&sse_arr[tid], 0.0f) + atomicAdd(&sse_arr[tid + 512], 0.0f);
#pragma unroll
        for (int off = 32; off > 0; off >>= 1) {
            t += __shfl_down(t, off, 64);
            s += __shfl_down(s, off, 64);
        }
        if (lane == 0) { red[wave] = t; red2[wave] = s; }
        __syncthreads();
        if (tid == 0) {
            float tot = 0.f, st = 0.f;
#pragma unroll
            for (int i = 0; i < 8; ++i) { tot += red[i]; st += red2[i]; }
            out[0] = (1.f + BETA) * st / (float)NELEM;
            out[out_size - 1] = expf(-tot);
        }
    }
}

extern "C" void kernel_launch(void* const* d_in, const int* in_sizes, int n_in,
                              void* d_out, int out_size, void* d_ws, size_t ws_size,
                              hipStream_t stream) {
    const float* z = (const float*)d_in[0];
    const float* E = (const float*)d_in[1];
    float* out = (float*)d_out;

    float* wsf = (float*)d_ws;
    unsigned int* ticket = (unsigned int*)wsf;         // [0] (+pad)
    unsigned int* counts = (unsigned int*)(wsf + 4);   // 512 uints
    float* sse_arr = wsf + 4 + K;                      // 1024 floats (written unconditionally)

    hipMemsetAsync(d_ws, 0, (4 + K) * sizeof(float), stream);   // ticket + counts
    vq_one<<<NBLK, 512, 0, stream>>>(z, E, out, out_size, sse_arr, counts, ticket);
}